// Round 4
// baseline (845.765 us; speedup 1.0000x reference)
//
#include <hip/hip_runtime.h>

// MLPDecoder_Causal: B=8,N=32,T=32,D=4,K=2,H=256,P=4,E=992.
// R9: schedule fix. R8 post-mortem: MFMA/3 + traffic/2 changed NOTHING (664->668)
// -> steps are ~160us latency-bound (floors ~50us): 16 waves/CU, 2 serial k-iters,
// ~10 barriers, probable layer1 spills under launch_bounds(256,4).
// This round:
//  - 512-thread blocks; k=0 and k=1 computed by PARALLEL wave-groups (g=tid>>8)
//    -> barrier critical path halved.
//  - M=32 rows/block (2048 blocks): layer1 4x8/thread (32 VGPR), MFMA acc 2x4
//    (32 VGPR); launch_bounds(512,7) caps 73 VGPR, peak live ~55 -> no spills,
//    24 waves/CU (1.5x R8) + 2x blocks for slack.
//  - tail output-MLP split across all 8 waves (partial dots + LDS combine).
// Numerics identical to R8 (fp16 W2 MFMA, fp16 Wo1/Wo2, fp32 layer1).
typedef unsigned short u16;
typedef unsigned int   u32;
typedef unsigned long long u64;
typedef __attribute__((ext_vector_type(8))) _Float16 f16x8;
typedef __attribute__((ext_vector_type(4))) float f32x4;

__device__ __forceinline__ float bf2f(u16 s){ u32 u = ((u32)s)<<16; float f; __builtin_memcpy(&f,&u,4); return f; }
__device__ __forceinline__ u16 f2h(float f){ _Float16 h = (_Float16)f; return __builtin_bit_cast(u16, h); }
// generic input accessor (prep only): F=1 -> memory is bf16, F=0 -> fp32
__device__ __forceinline__ float inV(const void* p, int i, int F){
  return F ? bf2f(((const u16*)p)[i]) : ((const float*)p)[i];
}

// wave0 scans first 512 u16 of `inputs`: bf16 N(0,1) data never has exponent
// field >= 0xA0; fp32 low-halves hit that ~37% of the time.
__device__ __forceinline__ void detect_bf16(const void* inputs0, int tid, int* flagL){
  if (tid < 64){
    const uint4* dp = (const uint4*)inputs0;
    uint4 v = dp[tid];
    u32 wds[4] = {v.x, v.y, v.z, v.w};
    int sus = 0;
#pragma unroll
    for (int i2=0; i2<4; ++i2){
      u32 wv = wds[i2];
      u32 h0 = wv & 0xffffu, h1 = wv >> 16;
      if (((h0>>7)&0xffu) >= 0xA0u) sus = 1;
      if (((h1>>7)&0xffu) >= 0xA0u) sus = 1;
    }
    u64 bal = __ballot(sus);
    if (tid == 0) *flagL = (bal == 0ull) ? 1 : 0;
  }
}

// ---------------- workspace layout (bytes) ----------------
#define WS_LAST0 0
#define WS_LAST1 32768
#define WS_WF    65536        // fp32 misc, 8648 floats
#define WS_W2P   102400       // W2 fp16 fragment pack, 131072 u16 = 256KB
#define WS_WO1T  364544       // Wo1^T fp16 [256][264], 135168 B
#define WS_WO2T  499712       // Wo2^T fp16 [256][256], 131072 B

// wf offsets (floats)
#define WF_W1   0             // [k][kd][c]  2*8*256
#define WF_B1   4096          // 2*256
#define WF_B2   4608          // 2*256
#define WF_WO3  5120          // [i][d] 256*4
#define WF_BO1  6144          // 256
#define WF_BO2  6400          // 256
#define WF_BO3  6656          // 4 (+4 pad)
#define WF_EV   6664          // [e][k] 992*2 softmax probs

// prep flat-work partition
#define PR_MISC 6660
#define PR_EV   (PR_MISC + 992)      // 7652
#define PR_L0   (PR_EV + 8192)      // 15844
#define PR_RO   (PR_L0 + 15872)     // 31716
#define PR_W2P  (PR_RO + 131072)    // 162788
#define PR_WO1T (PR_W2P + 67584)    // 230372
#define PR_WO2T (PR_WO1T + 65536)   // 295908

// ---------------- prep: dtype-resolve + pack everything once ----------------
__global__ void k_prep(const void* __restrict__ inputs, const void* __restrict__ rel_graph,
                       const void* __restrict__ gumbel,
                       const void* __restrict__ W1, const void* __restrict__ b1,
                       const void* __restrict__ W2, const void* __restrict__ b2,
                       const void* __restrict__ Wo1, const void* __restrict__ bo1,
                       const void* __restrict__ Wo2, const void* __restrict__ bo2,
                       const void* __restrict__ Wo3, const void* __restrict__ bo3,
                       float* __restrict__ wf, u16* __restrict__ w2p,
                       u16* __restrict__ wo1t, u16* __restrict__ wo2t,
                       float* __restrict__ last0, float* __restrict__ out)
{
  __shared__ int flagL;
  int tid = threadIdx.x;
  detect_bf16(inputs, tid, &flagL);
  __syncthreads();
  const int F = flagL;
  int i = blockIdx.x*256 + tid;
  if (i < PR_MISC){                    // fp32 cache, flat index == wf index
    const void* src; int off;
    if      (i < 4096) { src = W1;  off = i; }
    else if (i < 4608) { src = b1;  off = i-4096; }
    else if (i < 5120) { src = b2;  off = i-4608; }
    else if (i < 6144) { src = Wo3; off = i-5120; }
    else if (i < 6400) { src = bo1; off = i-6144; }
    else if (i < 6656) { src = bo2; off = i-6400; }
    else               { src = bo3; off = i-6656; }
    wf[i] = inV(src, off, F);
    return;
  }
  if (i < PR_EV){                      // softmax((rel+gumbel)/0.5), K=2
    int e = i - PR_MISC;
    float l0 = (inV(rel_graph,2*e,F)   + inV(gumbel,2*e,F))   * 2.f;
    float l1 = (inV(rel_graph,2*e+1,F) + inV(gumbel,2*e+1,F)) * 2.f;
    float m = fmaxf(l0,l1);
    float e0 = __expf(l0-m), e1 = __expf(l1-m), s = 1.f/(e0+e1);
    wf[WF_EV+2*e]   = e0*s;
    wf[WF_EV+2*e+1] = e1*s;
    return;
  }
  if (i < PR_L0){                      // last0[bt][n][d] = inputs[b, n, 4*tp, d]
    int j = i - PR_EV;
    int d = j&3, nn = (j>>2)&31, bt = j>>7, b = bt>>3, tp = bt&7;
    last0[j] = inV(inputs, b*4096 + nn*128 + tp*16 + d, F);
    return;
  }
  if (i < PR_RO){                      // rel_out broadcast
    int j = i - PR_L0;
    out[31744 + j] = inV(rel_graph, j % 1984, F);
    return;
  }
  if (i < PR_W2P){                     // W2 -> fp16 fragment pack
    // flat: (((k*16 + t)*8 + q)*64 + l)*8 + ei
    int e = i - PR_RO;
    int ei = e & 7, l = (e>>3)&63, q = (e>>9)&7, t = (e>>12)&15, k = e>>16;
    int kk  = q*32 + (l>>4)*8 + ei;    // contraction index (h1 col)
    int col = t*16 + (l&15);           // output col
    w2p[e] = f2h(inV(W2, k*65536 + kk*256 + col, F));
    return;
  }
  if (i < PR_WO1T){                    // Wo1^T fp16 [c][264], pad i>=260 -> 0
    int e = i - PR_W2P;
    int c = e / 264, ii = e - c*264;
    wo1t[e] = (ii < 260) ? f2h(inV(Wo1, ii*256 + c, F)) : (u16)0;
    return;
  }
  if (i < PR_WO2T){                    // Wo2^T fp16 [c][256]
    int e = i - PR_WO1T;
    int c = e >> 8, ii = e & 255;
    wo2t[e] = f2h(inV(Wo2, ii*256 + c, F));
  }
}

// ---------------- k_fused: edge MLP + aggregate + output MLP ----------------
// LDS float offsets
#define S_XJ    0       // xj[32][8]
#define S_EV    256     // evL[32][2]
#define S_AGGP  320     // aggP[8][64]
#define S_AUG   832     // augT[264]
#define S_RGN   1096    // union{ frags uint4[2][16][64] ; hookT[31*260] ; pbuf/o1T/o2T }
#define S_PB    (S_RGN)        // pbuf[2][256]
#define S_O1    (S_RGN + 512)  // o1T[256]
#define S_O2    (S_RGN + 768)  // o2T[256]
#define S_TOT   9288           // 37152 B

// block = (bt, receiver n); 8 waves; wave-group g = tid>>8 handles k=g.
__global__ __launch_bounds__(512, 7) void k_fused(
    const float* __restrict__ lastIn, float* __restrict__ lastOut,
    const float* __restrict__ wf, const u16* __restrict__ w2p,
    const u16* __restrict__ wo1t, const u16* __restrict__ wo2t,
    float* __restrict__ hooks, float* __restrict__ out0, int pstep)
{
  __shared__ __align__(16) float sm[S_TOT];
  uint4* frag  = (uint4*)(sm + S_RGN);   // [g*1024 + (rt*8+q)*64 + slot]
  float* hookT = sm + S_RGN;             // [row*260 + col]

  const int tid = threadIdx.x;
  const int n = blockIdx.x & 31, bt = blockIdx.x >> 5;
  const int b = bt>>3, tp = bt&7;
  const int g = tid >> 8;                // k handled by this wave-group
  const int gtid = tid & 255;
  const int rg = gtid & 7, cgi = gtid >> 3, c = cgi*8;
  const int lane = tid & 63, wave = tid >> 6, w4 = wave & 3;
  const int l15 = lane & 15, lg = lane >> 4;

  if (tid < 32){                   // xj staging: row tid = [send(4)|recv(4)]
    float4 sv = make_float4(0.f,0.f,0.f,0.f), rv = sv;
    if (tid < 31){
      int s = tid + (tid >= n);
      sv = *(const float4*)&lastIn[bt*128 + s*4];
      rv = *(const float4*)&lastIn[bt*128 + n*4];
    }
    *(float4*)&sm[S_XJ + tid*8]     = sv;
    *(float4*)&sm[S_XJ + tid*8 + 4] = rv;
  } else if (tid < 63){            // edge softmax
    int e = tid - 32;
    sm[S_EV + e*2]     = wf[WF_EV + 2*(n*31+e)];
    sm[S_EV + e*2 + 1] = wf[WF_EV + 2*(n*31+e) + 1];
  }
  __syncthreads();                 // B0

  // ---- layer1 fp32 VALU (group g does k=g): 4 rows x 8 cols per thread
  {
    float4 a0[4], a1[4];
    float4 bb0 = *(const float4*)&wf[WF_B1 + g*256 + c];
    float4 bb1 = *(const float4*)&wf[WF_B1 + g*256 + c + 4];
#pragma unroll
    for (int ri=0; ri<4; ++ri){ a0[ri] = bb0; a1[ri] = bb1; }
    const float* W1k = wf + WF_W1 + g*2048;
#pragma unroll
    for (int kd=0; kd<8; ++kd){
      float4 w0 = *(const float4*)&W1k[kd*256 + c];
      float4 w1 = *(const float4*)&W1k[kd*256 + c + 4];
#pragma unroll
      for (int ri=0; ri<4; ++ri){
        float xv = sm[S_XJ + (rg + 8*ri)*8 + kd];
        a0[ri].x += xv*w0.x; a0[ri].y += xv*w0.y; a0[ri].z += xv*w0.z; a0[ri].w += xv*w0.w;
        a1[ri].x += xv*w1.x; a1[ri].y += xv*w1.y; a1[ri].z += xv*w1.z; a1[ri].w += xv*w1.w;
      }
    }
    // relu + cvt fp16, store A-frags (lane-linear)
#pragma unroll
    for (int ri=0; ri<4; ++ri){
      int j = rg + 8*ri;
      f16x8 hv;
      hv[0] = (_Float16)fmaxf(a0[ri].x,0.f); hv[1] = (_Float16)fmaxf(a0[ri].y,0.f);
      hv[2] = (_Float16)fmaxf(a0[ri].z,0.f); hv[3] = (_Float16)fmaxf(a0[ri].w,0.f);
      hv[4] = (_Float16)fmaxf(a1[ri].x,0.f); hv[5] = (_Float16)fmaxf(a1[ri].y,0.f);
      hv[6] = (_Float16)fmaxf(a1[ri].z,0.f); hv[7] = (_Float16)fmaxf(a1[ri].w,0.f);
      int fi   = ((j>>4)<<3) + (cgi>>2);      // rt*8 + q
      int slot = (j&15) + ((cgi&3)<<4);
      frag[g*1024 + fi*64 + slot] = __builtin_bit_cast(uint4, hv);
    }
  }
  __syncthreads();                 // B1: frags ready

  // ---- layer2 MFMA fp16: per wave 2 row-tiles x 4 col-tiles, k = g
  f32x4 acc[2][4];
#pragma unroll
  for (int nt=0; nt<4; ++nt){
    float bv = wf[WF_B2 + g*256 + (w4<<6) + (nt<<4) + l15];
    f32x4 bi = {bv,bv,bv,bv};
    acc[0][nt] = bi; acc[1][nt] = bi;
  }
  {
    const u16* Bbase = w2p + ((g*16 + (w4<<2))<<12) + (lane<<3);
#pragma unroll
    for (int q=0; q<8; ++q){
      uint4 Au0 = frag[g*1024 + q*64 + lane];
      uint4 Au1 = frag[g*1024 + (8+q)*64 + lane];
#pragma unroll
      for (int nt=0; nt<4; ++nt){
        f16x8 Bf = __builtin_bit_cast(f16x8, *(const uint4*)(Bbase + (nt<<12) + (q<<9)));
        acc[0][nt] = __builtin_amdgcn_mfma_f32_16x16x32_f16(
            __builtin_bit_cast(f16x8, Au0), Bf, acc[0][nt], 0,0,0);
        acc[1][nt] = __builtin_amdgcn_mfma_f32_16x16x32_f16(
            __builtin_bit_cast(f16x8, Au1), Bf, acc[1][nt], 0,0,0);
      }
    }
  }

  // ---- epilogue: m = relu(acc)*ev; per-lane col partials; wave reduce
  // D layout: row = 16*rt + 4*lg + r, col = 64*w4 + 16*nt + l15, k = g
  float aggl[4] = {0.f,0.f,0.f,0.f};
#pragma unroll
  for (int rt=0; rt<2; ++rt){
#pragma unroll
    for (int r=0; r<4; ++r){
      int row = (rt<<4) + (lg<<2) + r;
      if (row < 31){
        float ev = sm[S_EV + row*2 + g];
#pragma unroll
        for (int nt=0; nt<4; ++nt)
          aggl[nt] += fmaxf(acc[rt][nt][r], 0.f)*ev;
      }
    }
  }
#pragma unroll
  for (int nt=0; nt<4; ++nt){
    aggl[nt] += __shfl_xor(aggl[nt], 16);
    aggl[nt] += __shfl_xor(aggl[nt], 32);
  }
  if (lane < 16){
#pragma unroll
    for (int nt=0; nt<4; ++nt)
      sm[S_AGGP + (wave<<6) + (nt<<4) + lane] = aggl[nt];
  }
  __syncthreads();                 // B2: all MFMA/frag reads done, aggP ready

  if (g == 1){                     // hookT overlay write (k=1 messages)
#pragma unroll
    for (int rt=0; rt<2; ++rt){
#pragma unroll
      for (int r=0; r<4; ++r){
        int row = (rt<<4) + (lg<<2) + r;
        if (row < 31){
          float ev = sm[S_EV + row*2 + 1];
#pragma unroll
          for (int nt=0; nt<4; ++nt)
            hookT[row*260 + (w4<<6) + (nt<<4) + l15] = fmaxf(acc[rt][nt][r], 0.f)*ev;
        }
      }
    }
  }
  __syncthreads();                 // B3: hookT complete

  // ---- hooks global stores (8 waves x 4 rows) + augT build
  {
    int hb = (((pstep*8 + tp)*8 + b)*992 + n*31)*256;
#pragma unroll
    for (int it=0; it<4; ++it){
      int row = wave + (it<<3);
      if (row < 31){
        float4 v = *(const float4*)&hookT[row*260 + (lane<<2)];
        *(float4*)&hooks[hb + row*256 + (lane<<2)] = v;
      }
    }
  }
  if (tid < 256){
    sm[S_AUG + 4 + tid] = sm[S_AGGP + tid] + sm[S_AGGP + 256 + tid];
  } else if (tid < 260){
    sm[S_AUG + (tid-256)] = lastIn[bt*128 + n*4 + (tid-256)];
  } else if (tid < 264){
    sm[S_AUG + tid] = 0.f;         // pad cols 260..263 (Wo1T pad weights are 0)
  }
  __syncthreads();                 // B4: augT ready, hookT dead -> tail bufs

  // ---- output MLP: 512 threads = (half-of-dot ph, col)
  {
    const int col = tid & 255;     // ph == g
    const u16* wc = wo1t + col*264 + (g<<7);
    const float* xs = sm + S_AUG + (g<<7);
    float s = g ? wf[WF_BO1 + col] : 0.f;
    const int NIT = g ? 17 : 16;   // ph0: i 0..127, ph1: i 128..263
    for (int i=0; i<NIT; ++i){
      f16x8 hw = __builtin_bit_cast(f16x8, *(const uint4*)(wc + i*8));
      float4 x0 = *(const float4*)&xs[i*8];
      float4 x1 = *(const float4*)&xs[i*8 + 4];
      s += x0.x*(float)hw[0] + x0.y*(float)hw[1] + x0.z*(float)hw[2] + x0.w*(float)hw[3]
         + x1.x*(float)hw[4] + x1.y*(float)hw[5] + x1.z*(float)hw[6] + x1.w*(float)hw[7];
    }
    sm[S_PB + (g<<8) + col] = s;
  }
  __syncthreads();                 // B5
  if (tid < 256) sm[S_O1 + tid] = fmaxf(sm[S_PB + tid] + sm[S_PB + 256 + tid], 0.f);
  __syncthreads();                 // B6
  {
    const int col = tid & 255;
    const u16* wc = wo2t + col*256 + (g<<7);
    const float* xs = sm + S_O1 + (g<<7);
    float s = g ? wf[WF_BO2 + col] : 0.f;
    for (int i=0; i<16; ++i){
      f16x8 hw = __builtin_bit_cast(f16x8, *(const uint4*)(wc + i*8));
      float4 x0 = *(const float4*)&xs[i*8];
      float4 x1 = *(const float4*)&xs[i*8 + 4];
      s += x0.x*(float)hw[0] + x0.y*(float)hw[1] + x0.z*(float)hw[2] + x0.w*(float)hw[3]
         + x1.x*(float)hw[4] + x1.y*(float)hw[5] + x1.z*(float)hw[6] + x1.w*(float)hw[7];
    }
    sm[S_PB + (g<<8) + col] = s;
  }
  __syncthreads();                 // B7
  if (tid < 256) sm[S_O2 + tid] = fmaxf(sm[S_PB + tid] + sm[S_PB + 256 + tid], 0.f);
  __syncthreads();                 // B8
  if (tid < 64){                   // p = o2 @ Wo3 + bo3; residual; store
    int d = tid & 3, ch = tid >> 2;        // 16 chunks x 16 elems
    float p = 0.f;
#pragma unroll
    for (int ii=0; ii<16; ++ii){
      int i = ch*16 + ii;
      p += sm[S_O2 + i]*wf[WF_WO3 + i*4 + d];
    }
#pragma unroll
    for (int s2=4; s2<64; s2<<=1) p += __shfl_xor(p, s2);
    if (ch == 0){
      float lv = lastIn[bt*128 + n*4 + d] + p + wf[WF_BO3 + d];
      lastOut[bt*128 + n*4 + d] = lv;
      int t = tp*4 + pstep;
      if (t < 31) out0[b*3968 + n*124 + t*4 + d] = lv;
    }
  }
}

extern "C" void kernel_launch(void* const* d_in, const int* in_sizes, int n_in,
                              void* d_out, int out_size, void* d_ws, size_t ws_size,
                              hipStream_t stream) {
  const void* inputs    = d_in[0];
  const void* rel_graph = d_in[1];
  const void* W1  = d_in[2];
  const void* b1  = d_in[3];
  const void* W2  = d_in[4];
  const void* b2  = d_in[5];
  const void* Wo1 = d_in[6];
  const void* bo1 = d_in[7];
  const void* Wo2 = d_in[8];
  const void* bo2 = d_in[9];
  const void* Wo3 = d_in[10];
  const void* bo3 = d_in[11];
  const void* gumbel = d_in[14];
  float* out = (float*)d_out;
  char* ws = (char*)d_ws;
  float* L0   = (float*)(ws + WS_LAST0);
  float* L1   = (float*)(ws + WS_LAST1);
  float* wf   = (float*)(ws + WS_WF);
  u16*   w2p  = (u16*)  (ws + WS_W2P);
  u16*   wo1t = (u16*)  (ws + WS_WO1T);
  u16*   wo2t = (u16*)  (ws + WS_WO2T);

  k_prep<<<(PR_WO2T + 255)/256, 256, 0, stream>>>(
      inputs, rel_graph, gumbel, W1, b1, W2, b2, Wo1, bo1, Wo2, bo2, Wo3, bo3,
      wf, w2p, wo1t, wo2t, L0, out);
  for (int p = 0; p < 4; ++p) {
    const float* lin  = (p & 1) ? L1 : L0;
    float*       lout = (p & 1) ? L0 : L1;
    k_fused<<<2048, 512, 0, stream>>>(lin, lout, wf, w2p, wo1t, wo2t,
                                      out + 47616, out, p);
  }
}